// Round 3
// baseline (6234.009 us; speedup 1.0000x reference)
//
#include <hip/hip_runtime.h>
#include <math.h>

#define F_FRAMES 1021
#define BATCH 16
#define T_LEN 262144
#define FREQn 513
#define HID 128
#define ENCn 256
#define BF (BATCH * F_FRAMES)  // 16336

typedef float v2f __attribute__((ext_vector_type(2)));

__device__ __forceinline__ float sigmoidf_(float x) {
  return 1.f / (1.f + __expf(-x));
}
__device__ __forceinline__ float tanhf_(float x) {
  // 1 - 2/(e^{2x}+1): monotone, no NaN for any finite x
  return 1.f - 2.f / (__expf(2.f * x) + 1.f);
}

// ---------------- STFT: frame + window + rfft(1024) -> mag, cos(phase), sin(phase)
__global__ __launch_bounds__(256) void stft_kernel(
    const float* __restrict__ x, float* __restrict__ mag,
    float* __restrict__ cosp, float* __restrict__ sinp) {
  __shared__ float zr[512], zi[512];
  int bf = blockIdx.x;
  int b = bf / F_FRAMES;
  int f = bf - b * F_FRAMES;
  const float* xb = x + (size_t)b * T_LEN + (size_t)f * 256;
  int tid = threadIdx.x;
  const float wstep = 6.28318530717958647692f / 1024.f;
#pragma unroll
  for (int u = 0; u < 2; ++u) {
    int j = tid + u * 256;
    int n = __brev((unsigned)j) >> 23;  // 9-bit bit-reverse
    float x0 = xb[2 * n] * (0.5f - 0.5f * __cosf((float)(2 * n) * wstep));
    float x1 = xb[2 * n + 1] * (0.5f - 0.5f * __cosf((float)(2 * n + 1) * wstep));
    zr[j] = x0;
    zi[j] = x1;
  }
  __syncthreads();
#pragma unroll
  for (int s = 1; s <= 9; ++s) {
    int half = 1 << (s - 1);
    int t = tid & (half - 1);
    int g = tid >> (s - 1);
    int pos = (g << s) + t;
    float ang = (float)t * (3.14159265358979323846f / (float)half);
    float sn, cs;
    __sincosf(ang, &sn, &cs);
    float wr = cs, wi = -sn;
    float ar = zr[pos], ai = zi[pos];
    float br = zr[pos + half], bi = zi[pos + half];
    float tr = wr * br - wi * bi;
    float ti = wr * bi + wi * br;
    zr[pos] = ar + tr;
    zi[pos] = ai + ti;
    zr[pos + half] = ar - tr;
    zi[pos + half] = ai - ti;
    __syncthreads();
  }
  const float eps = 1.1920928955078125e-07f;
  for (int k = tid; k < 513; k += 256) {
    int ka = k & 511;
    int kb = (512 - k) & 511;
    float zar = zr[ka], zai = zi[ka];
    float zbr = zr[kb], zbi = zi[kb];
    float Zer = 0.5f * (zar + zbr);
    float Zei = 0.5f * (zai - zbi);
    float Zor = 0.5f * (zai + zbi);
    float Zoi = -0.5f * (zar - zbr);
    float ang = (float)k * (3.14159265358979323846f / 512.f);
    float sn, cs;
    __sincosf(ang, &sn, &cs);
    float Wr = cs, Wi = -sn;
    float re = Zer + Wr * Zor - Wi * Zoi;
    float im = Zei + Wr * Zoi + Wi * Zor;
    size_t idx = (size_t)bf * FREQn + k;
    float p2 = re * re + im * im;
    mag[idx] = sqrtf(fmaxf(p2, eps));
    float rr = re + eps, ii = im + eps;
    float inv = rsqrtf(rr * rr + ii * ii);
    cosp[idx] = rr * inv;
    sinp[idx] = ii * inv;
  }
}

// ---------------- iSTFT: est spectrum -> irfft(1024) frames
__global__ __launch_bounds__(256) void istft_kernel(
    const float* __restrict__ er, const float* __restrict__ ei,
    float* __restrict__ y) {
  __shared__ float xr[513], xi[513];
  __shared__ float zr[512], zi[512];
  int bf = blockIdx.x;
  int tid = threadIdx.x;
  for (int k = tid; k < 513; k += 256) {
    size_t idx = (size_t)bf * FREQn + k;
    xr[k] = er[idx];
    float v = ei[idx];
    xi[k] = (k == 0 || k == 512) ? 0.f : v;  // pocketfft c2r ignores DC/Nyquist imag
  }
  __syncthreads();
#pragma unroll
  for (int u = 0; u < 2; ++u) {
    int k = tid + u * 256;  // 0..511
    int kk = 512 - k;
    float Xkr = xr[k], Xki = xi[k];
    float Xbr = xr[kk], Xbi = xi[kk];
    float Zer = 0.5f * (Xkr + Xbr);
    float Zei = 0.5f * (Xki - Xbi);
    float Vr = 0.5f * (Xkr - Xbr);
    float Vi = 0.5f * (Xki + Xbi);
    float ang = (float)k * (3.14159265358979323846f / 512.f);
    float sn, cs;
    __sincosf(ang, &sn, &cs);
    float Zor = cs * Vr - sn * Vi;  // e^{+i pi k/512} * V
    float Zoi = cs * Vi + sn * Vr;
    float Rr = Zer - Zoi;  // Z = Ze + i*Zo
    float Ri = Zei + Zor;
    int d = __brev((unsigned)k) >> 23;
    zr[d] = Rr;
    zi[d] = Ri;
  }
  __syncthreads();
#pragma unroll
  for (int s = 1; s <= 9; ++s) {
    int half = 1 << (s - 1);
    int t = tid & (half - 1);
    int g = tid >> (s - 1);
    int pos = (g << s) + t;
    float ang = (float)t * (3.14159265358979323846f / (float)half);
    float sn, cs;
    __sincosf(ang, &sn, &cs);
    float wr = cs, wi = sn;  // conjugate twiddles => unnormalized IDFT
    float ar = zr[pos], ai = zi[pos];
    float br = zr[pos + half], bi = zi[pos + half];
    float tr = wr * br - wi * bi;
    float ti = wr * bi + wi * br;
    zr[pos] = ar + tr;
    zi[pos] = ai + ti;
    zr[pos + half] = ar - tr;
    zi[pos + half] = ai - ti;
    __syncthreads();
  }
  const float sc = 1.f / 512.f;
  float2* y2 = (float2*)(y + (size_t)bf * 1024);
#pragma unroll
  for (int u = 0; u < 2; ++u) {
    int n = tid + u * 256;
    y2[n] = make_float2(zr[n] * sc, zi[n] * sc);
  }
}

// ---------------- generic fp32 GEMM: C[M,N] = A[M,K] @ W[N,K]^T (+bias)(+epilogue)
// MODE 0: C = v            (bias optional)
// MODE 1: s = sigmoid(v); em = s*aux1; aux2 *= em; aux3 *= em   (mask1 -> est re/im)
// MODE 2: s = sigmoid(v); C = s*aux1                             (mask2 -> est2)
template <int MODE>
__global__ __launch_bounds__(256) void gemm_nt(
    const float* __restrict__ A, const float* __restrict__ W,
    const float* __restrict__ bias, float* __restrict__ C, int M, int N, int K,
    const float* __restrict__ aux1, float* __restrict__ aux2,
    float* __restrict__ aux3) {
  __shared__ float As[16][68];
  __shared__ float Ws[16][68];
  int tid = threadIdx.x;
  int tx = tid & 15, ty = tid >> 4;
  int m0 = blockIdx.y * 64, n0 = blockIdx.x * 64;
  float acc[4][4] = {};
  int klc = tid & 15;
  int rl = tid >> 4;
  for (int k0 = 0; k0 < K; k0 += 16) {
#pragma unroll
    for (int r = 0; r < 4; ++r) {
      int row = rl + r * 16;
      int m = m0 + row;
      int k = k0 + klc;
      As[klc][row] = (m < M && k < K) ? A[(size_t)m * K + k] : 0.f;
      int n = n0 + row;
      Ws[klc][row] = (n < N && k < K) ? W[(size_t)n * K + k] : 0.f;
    }
    __syncthreads();
#pragma unroll
    for (int kk = 0; kk < 16; ++kk) {
      float4 a4 = *reinterpret_cast<const float4*>(&As[kk][ty * 4]);
      float4 w4 = *reinterpret_cast<const float4*>(&Ws[kk][tx * 4]);
      float av[4] = {a4.x, a4.y, a4.z, a4.w};
      float wv[4] = {w4.x, w4.y, w4.z, w4.w};
#pragma unroll
      for (int i = 0; i < 4; ++i)
#pragma unroll
        for (int j = 0; j < 4; ++j)
          acc[i][j] = fmaf(av[i], wv[j], acc[i][j]);
    }
    __syncthreads();
  }
#pragma unroll
  for (int i = 0; i < 4; ++i) {
    int m = m0 + ty * 4 + i;
    if (m >= M) continue;
#pragma unroll
    for (int j = 0; j < 4; ++j) {
      int n = n0 + tx * 4 + j;
      if (n >= N) continue;
      float v = acc[i][j];
      if (bias) v += bias[n];
      size_t idx = (size_t)m * N + n;
      if (MODE == 0) {
        C[idx] = v;
      } else if (MODE == 1) {
        float s = sigmoidf_(v);
        float em = s * aux1[idx];
        aux2[idx] = em * aux2[idx];
        aux3[idx] = em * aux3[idx];
      } else {
        float s = sigmoidf_(v);
        C[idx] = s * aux1[idx];
      }
    }
  }
}

// ---------------- GRU recurrent scan (input gates xg precomputed)
// one block per batch element; 384 threads = one gate row each.
// Whh row pinned in VGPRs (launch_bounds(384,1) lifts the VGPR cap to 256;
// asm pin prevents rematerialization from global). Packed fp32 FMA dot.
__global__ __launch_bounds__(384, 1) void gru_scan(
    const float* __restrict__ xg,   // [B, F, 384]
    const float* __restrict__ Whh,  // [384, 128]
    const float* __restrict__ bhh,  // [384]
    const float* __restrict__ h0,   // [B, 128]
    float* __restrict__ hout,       // [B, F, 128]
    float* __restrict__ hlast,      // [B, 128]
    int F) {
  __shared__ __align__(16) float h_s[128];
  __shared__ float a_s[384];
  __shared__ float xn_s[128];
  int b = blockIdx.x;
  int g = threadIdx.x;
  // Whh row g in registers as 64 packed float2 (rows are 512B-aligned)
  v2f w[64];
  {
    const v2f* wrow = reinterpret_cast<const v2f*>(Whh + (size_t)g * 128);
#pragma unroll
    for (int k = 0; k < 64; ++k) w[k] = wrow[k];
  }
  // pin: forbid rematerialization / re-load of weights
#pragma unroll
  for (int k = 0; k < 64; ++k) asm volatile("" : "+v"(w[k]));
  float bh = bhh[g];
  if (g < 128) h_s[g] = h0[b * 128 + g];
  const float* xgb = xg + (size_t)b * F * 384 + g;
  float* hob = hout + (size_t)b * F * 128;
  float xv_cur = xgb[0];
  __syncthreads();
  for (int t = 0; t < F; ++t) {
    // prefetch next step's input gate (hides L2 latency under the dot)
    float xv_nxt = (t + 1 < F) ? xgb[(size_t)(t + 1) * 384] : 0.f;
    const v2f* h2 = reinterpret_cast<const v2f*>(h_s);
    v2f a0 = {0.f, 0.f}, a1 = {0.f, 0.f}, a2 = {0.f, 0.f}, a3 = {0.f, 0.f};
    v2f a4 = {0.f, 0.f}, a5 = {0.f, 0.f}, a6 = {0.f, 0.f}, a7 = {0.f, 0.f};
#pragma unroll
    for (int k = 0; k < 64; k += 8) {
      a0 = __builtin_elementwise_fma(w[k + 0], h2[k + 0], a0);
      a1 = __builtin_elementwise_fma(w[k + 1], h2[k + 1], a1);
      a2 = __builtin_elementwise_fma(w[k + 2], h2[k + 2], a2);
      a3 = __builtin_elementwise_fma(w[k + 3], h2[k + 3], a3);
      a4 = __builtin_elementwise_fma(w[k + 4], h2[k + 4], a4);
      a5 = __builtin_elementwise_fma(w[k + 5], h2[k + 5], a5);
      a6 = __builtin_elementwise_fma(w[k + 6], h2[k + 6], a6);
      a7 = __builtin_elementwise_fma(w[k + 7], h2[k + 7], a7);
    }
    v2f s01 = a0 + a1, s23 = a2 + a3, s45 = a4 + a5, s67 = a6 + a7;
    v2f s = (s01 + s23) + (s45 + s67);
    float acc = bh + s.x + s.y;
    if (g < 256) {
      a_s[g] = xv_cur + acc;
    } else {
      a_s[g] = acc;
      xn_s[g - 256] = xv_cur;
    }
    __syncthreads();
    if (g < 128) {
      float r = sigmoidf_(a_s[g]);
      float z = sigmoidf_(a_s[128 + g]);
      float nv = tanhf_(xn_s[g] + r * a_s[256 + g]);
      float hn = (1.f - z) * nv + z * h_s[g];
      h_s[g] = hn;
      hob[(size_t)t * 128 + g] = hn;
    }
    xv_cur = xv_nxt;
    __syncthreads();
  }
  if (g < 128) hlast[b * 128 + g] = h_s[g];
}

// ---------------- instant layernorm over channels (256)
__global__ __launch_bounds__(256) void ln_kernel(
    const float* __restrict__ enc, const float* __restrict__ gamma,
    const float* __restrict__ beta, float* __restrict__ out) {
  int row = blockIdx.x * 4 + (threadIdx.x >> 6);
  int lane = threadIdx.x & 63;
  const float* p = enc + (size_t)row * ENCn;
  float4 v = *reinterpret_cast<const float4*>(p + lane * 4);
  float s = v.x + v.y + v.z + v.w;
  float ss = v.x * v.x + v.y * v.y + v.z * v.z + v.w * v.w;
#pragma unroll
  for (int o = 32; o > 0; o >>= 1) {
    s += __shfl_down(s, o);
    ss += __shfl_down(ss, o);
  }
  s = __shfl(s, 0);
  ss = __shfl(ss, 0);
  float mean = s * (1.f / 256.f);
  float var = ss * (1.f / 256.f) - mean * mean;
  float rstd = rsqrtf(var + 1e-7f);
  float4 g4 = *reinterpret_cast<const float4*>(gamma + lane * 4);
  float4 b4 = *reinterpret_cast<const float4*>(beta + lane * 4);
  float4 o4;
  o4.x = (v.x - mean) * rstd * g4.x + b4.x;
  o4.y = (v.y - mean) * rstd * g4.y + b4.y;
  o4.z = (v.z - mean) * rstd * g4.z + b4.z;
  o4.w = (v.w - mean) * rstd * g4.w + b4.w;
  *reinterpret_cast<float4*>(out + (size_t)row * ENCn + lane * 4) = o4;
}

// ---------------- overlap-add
__global__ __launch_bounds__(256) void ola_kernel(const float* __restrict__ dec,
                                                  float* __restrict__ out) {
  int idx = blockIdx.x * 256 + threadIdx.x;  // b*T + n
  int b = idx >> 18;                          // T = 2^18
  int n = idx & (T_LEN - 1);
  int f0 = (n < 768) ? 0 : ((n - 768) >> 8);
  int f1 = min(n >> 8, F_FRAMES - 1);
  float s = 0.f;
  for (int f = f0; f <= f1; ++f)
    s += dec[((size_t)b * F_FRAMES + f) * 1024 + (n - (f << 8))];
  out[idx] = s;
}

extern "C" void kernel_launch(void* const* d_in, const int* in_sizes, int n_in,
                              void* d_out, int out_size, void* d_ws,
                              size_t ws_size, hipStream_t stream) {
  const float* x = (const float*)d_in[0];
  const float* in_st1 = (const float*)d_in[1];
  const float* in_st2 = (const float*)d_in[2];
  const float* s1_Wih1 = (const float*)d_in[3];
  const float* s1_Whh1 = (const float*)d_in[4];
  const float* s1_bih1 = (const float*)d_in[5];
  const float* s1_bhh1 = (const float*)d_in[6];
  const float* s1_Wih2 = (const float*)d_in[7];
  const float* s1_Whh2 = (const float*)d_in[8];
  const float* s1_bih2 = (const float*)d_in[9];
  const float* s1_bhh2 = (const float*)d_in[10];
  const float* s1_Wd = (const float*)d_in[11];
  const float* s1_bd = (const float*)d_in[12];
  const float* enc_W = (const float*)d_in[13];
  const float* gamma = (const float*)d_in[14];
  const float* beta = (const float*)d_in[15];
  const float* s2_Wih1 = (const float*)d_in[16];
  const float* s2_Whh1 = (const float*)d_in[17];
  const float* s2_bih1 = (const float*)d_in[18];
  const float* s2_bhh1 = (const float*)d_in[19];
  const float* s2_Wih2 = (const float*)d_in[20];
  const float* s2_Whh2 = (const float*)d_in[21];
  const float* s2_bih2 = (const float*)d_in[22];
  const float* s2_bhh2 = (const float*)d_in[23];
  const float* s2_Wd = (const float*)d_in[24];
  const float* s2_bd = (const float*)d_in[25];
  const float* dec_W = (const float*)d_in[26];

  float* out = (float*)d_out;
  float* st_out = out + (size_t)BATCH * T_LEN;  // [2,16,128] + [2,16,128]

  float* ws = (float*)d_ws;
  float* mag = ws;                              // BF*513
  float* cosp = mag + (size_t)BF * FREQn;       // BF*513 (-> est_re)
  float* sinp = cosp + (size_t)BF * FREQn;      // BF*513 (-> est_im)
  float* xgA = sinp + (size_t)BF * FREQn;       // BF*384
  float* xgB = xgA + (size_t)BF * 384;          // BF*384
  float* h1 = xgB + (size_t)BF * 384;           // BF*128
  float* h2 = h1 + (size_t)BF * HID;            // BF*128
  float* ybuf = h2 + (size_t)BF * HID;          // BF*1024 (y1, then dec)
  float* enc = ybuf + (size_t)BF * 1024;        // BF*256
  float* encn = enc + (size_t)BF * ENCn;        // BF*256 (enc_norm, then est2)

  auto gg = [](int M, int N) { return dim3((N + 63) / 64, (M + 63) / 64); };

  // 1. STFT -> mag, cos, sin
  stft_kernel<<<BF, 256, 0, stream>>>(x, mag, cosp, sinp);
  // 2. sep1 GRU-a input gates
  gemm_nt<0><<<gg(BF, 384), 256, 0, stream>>>(mag, s1_Wih1, s1_bih1, xgA, BF,
                                              384, FREQn, nullptr, nullptr,
                                              nullptr);
  // 3. scan a
  gru_scan<<<BATCH, 384, 0, stream>>>(xgA, s1_Whh1, s1_bhh1, in_st1, h1,
                                      st_out, F_FRAMES);
  // 4. sep1 GRU-b input gates
  gemm_nt<0><<<gg(BF, 384), 256, 0, stream>>>(h1, s1_Wih2, s1_bih2, xgB, BF,
                                              384, HID, nullptr, nullptr,
                                              nullptr);
  // 5. scan b
  gru_scan<<<BATCH, 384, 0, stream>>>(xgB, s1_Whh2, s1_bhh2, in_st1 + 2048, h2,
                                      st_out + 2048, F_FRAMES);
  // 6. mask1 dense + est spectrum (overwrites cosp/sinp)
  gemm_nt<1><<<gg(BF, FREQn), 256, 0, stream>>>(h2, s1_Wd, s1_bd, nullptr, BF,
                                                FREQn, HID, mag, cosp, sinp);
  // 7. iSTFT -> y1
  istft_kernel<<<BF, 256, 0, stream>>>(cosp, sinp, ybuf);
  // 8. encoder
  gemm_nt<0><<<gg(BF, ENCn), 256, 0, stream>>>(ybuf, enc_W, nullptr, enc, BF,
                                               ENCn, 1024, nullptr, nullptr,
                                               nullptr);
  // 9. instant LN
  ln_kernel<<<BF / 4, 256, 0, stream>>>(enc, gamma, beta, encn);
  // 10. sep2 GRU-a input gates
  gemm_nt<0><<<gg(BF, 384), 256, 0, stream>>>(encn, s2_Wih1, s2_bih1, xgA, BF,
                                              384, ENCn, nullptr, nullptr,
                                              nullptr);
  // 11. scan 2a
  gru_scan<<<BATCH, 384, 0, stream>>>(xgA, s2_Whh1, s2_bhh1, in_st2, h1,
                                      st_out + 4096, F_FRAMES);
  // 12. sep2 GRU-b input gates
  gemm_nt<0><<<gg(BF, 384), 256, 0, stream>>>(h1, s2_Wih2, s2_bih2, xgB, BF,
                                              384, HID, nullptr, nullptr,
                                              nullptr);
  // 13. scan 2b
  gru_scan<<<BATCH, 384, 0, stream>>>(xgB, s2_Whh2, s2_bhh2, in_st2 + 2048, h2,
                                      st_out + 6144, F_FRAMES);
  // 14. mask2 -> est2 (reads enc, writes encn)
  gemm_nt<2><<<gg(BF, ENCn), 256, 0, stream>>>(h2, s2_Wd, s2_bd, encn, BF,
                                               ENCn, HID, enc, nullptr,
                                               nullptr);
  // 15. decoder (reuses ybuf)
  gemm_nt<0><<<gg(BF, 1024), 256, 0, stream>>>(encn, dec_W, nullptr, ybuf, BF,
                                               1024, ENCn, nullptr, nullptr,
                                               nullptr);
  // 16. overlap-add
  ola_kernel<<<(BATCH * T_LEN) / 256, 256, 0, stream>>>(ybuf, out);
}

// Round 4
// 5518.224 us; speedup vs baseline: 1.1297x; 1.1297x over previous
//
#include <hip/hip_runtime.h>
#include <math.h>

#define F_FRAMES 1021
#define BATCH 16
#define T_LEN 262144
#define FREQn 513
#define HID 128
#define ENCn 256
#define BF (BATCH * F_FRAMES)  // 16336

typedef float v4f __attribute__((ext_vector_type(4)));

__device__ __forceinline__ float sigmoidf_(float x) {
  return 1.f / (1.f + __expf(-x));
}
__device__ __forceinline__ float tanhf_(float x) {
  // 1 - 2/(e^{2x}+1): monotone, no NaN for any finite x
  return 1.f - 2.f / (__expf(2.f * x) + 1.f);
}

// ---------------- STFT: frame + window + rfft(1024) -> mag, cos(phase), sin(phase)
__global__ __launch_bounds__(256) void stft_kernel(
    const float* __restrict__ x, float* __restrict__ mag,
    float* __restrict__ cosp, float* __restrict__ sinp) {
  __shared__ float zr[512], zi[512];
  int bf = blockIdx.x;
  int b = bf / F_FRAMES;
  int f = bf - b * F_FRAMES;
  const float* xb = x + (size_t)b * T_LEN + (size_t)f * 256;
  int tid = threadIdx.x;
  const float wstep = 6.28318530717958647692f / 1024.f;
#pragma unroll
  for (int u = 0; u < 2; ++u) {
    int j = tid + u * 256;
    int n = __brev((unsigned)j) >> 23;  // 9-bit bit-reverse
    float x0 = xb[2 * n] * (0.5f - 0.5f * __cosf((float)(2 * n) * wstep));
    float x1 = xb[2 * n + 1] * (0.5f - 0.5f * __cosf((float)(2 * n + 1) * wstep));
    zr[j] = x0;
    zi[j] = x1;
  }
  __syncthreads();
#pragma unroll
  for (int s = 1; s <= 9; ++s) {
    int half = 1 << (s - 1);
    int t = tid & (half - 1);
    int g = tid >> (s - 1);
    int pos = (g << s) + t;
    float ang = (float)t * (3.14159265358979323846f / (float)half);
    float sn, cs;
    __sincosf(ang, &sn, &cs);
    float wr = cs, wi = -sn;
    float ar = zr[pos], ai = zi[pos];
    float br = zr[pos + half], bi = zi[pos + half];
    float tr = wr * br - wi * bi;
    float ti = wr * bi + wi * br;
    zr[pos] = ar + tr;
    zi[pos] = ai + ti;
    zr[pos + half] = ar - tr;
    zi[pos + half] = ai - ti;
    __syncthreads();
  }
  const float eps = 1.1920928955078125e-07f;
  for (int k = tid; k < 513; k += 256) {
    int ka = k & 511;
    int kb = (512 - k) & 511;
    float zar = zr[ka], zai = zi[ka];
    float zbr = zr[kb], zbi = zi[kb];
    float Zer = 0.5f * (zar + zbr);
    float Zei = 0.5f * (zai - zbi);
    float Zor = 0.5f * (zai + zbi);
    float Zoi = -0.5f * (zar - zbr);
    float ang = (float)k * (3.14159265358979323846f / 512.f);
    float sn, cs;
    __sincosf(ang, &sn, &cs);
    float Wr = cs, Wi = -sn;
    float re = Zer + Wr * Zor - Wi * Zoi;
    float im = Zei + Wr * Zoi + Wi * Zor;
    size_t idx = (size_t)bf * FREQn + k;
    float p2 = re * re + im * im;
    mag[idx] = sqrtf(fmaxf(p2, eps));
    float rr = re + eps, ii = im + eps;
    float inv = rsqrtf(rr * rr + ii * ii);
    cosp[idx] = rr * inv;
    sinp[idx] = ii * inv;
  }
}

// ---------------- iSTFT: est spectrum -> irfft(1024) frames
__global__ __launch_bounds__(256) void istft_kernel(
    const float* __restrict__ er, const float* __restrict__ ei,
    float* __restrict__ y) {
  __shared__ float xr[513], xi[513];
  __shared__ float zr[512], zi[512];
  int bf = blockIdx.x;
  int tid = threadIdx.x;
  for (int k = tid; k < 513; k += 256) {
    size_t idx = (size_t)bf * FREQn + k;
    xr[k] = er[idx];
    float v = ei[idx];
    xi[k] = (k == 0 || k == 512) ? 0.f : v;  // pocketfft c2r ignores DC/Nyquist imag
  }
  __syncthreads();
#pragma unroll
  for (int u = 0; u < 2; ++u) {
    int k = tid + u * 256;  // 0..511
    int kk = 512 - k;
    float Xkr = xr[k], Xki = xi[k];
    float Xbr = xr[kk], Xbi = xi[kk];
    float Zer = 0.5f * (Xkr + Xbr);
    float Zei = 0.5f * (Xki - Xbi);
    float Vr = 0.5f * (Xkr - Xbr);
    float Vi = 0.5f * (Xki + Xbi);
    float ang = (float)k * (3.14159265358979323846f / 512.f);
    float sn, cs;
    __sincosf(ang, &sn, &cs);
    float Zor = cs * Vr - sn * Vi;  // e^{+i pi k/512} * V
    float Zoi = cs * Vi + sn * Vr;
    float Rr = Zer - Zoi;  // Z = Ze + i*Zo
    float Ri = Zei + Zor;
    int d = __brev((unsigned)k) >> 23;
    zr[d] = Rr;
    zi[d] = Ri;
  }
  __syncthreads();
#pragma unroll
  for (int s = 1; s <= 9; ++s) {
    int half = 1 << (s - 1);
    int t = tid & (half - 1);
    int g = tid >> (s - 1);
    int pos = (g << s) + t;
    float ang = (float)t * (3.14159265358979323846f / (float)half);
    float sn, cs;
    __sincosf(ang, &sn, &cs);
    float wr = cs, wi = sn;  // conjugate twiddles => unnormalized IDFT
    float ar = zr[pos], ai = zi[pos];
    float br = zr[pos + half], bi = zi[pos + half];
    float tr = wr * br - wi * bi;
    float ti = wr * bi + wi * br;
    zr[pos] = ar + tr;
    zi[pos] = ai + ti;
    zr[pos + half] = ar - tr;
    zi[pos + half] = ai - ti;
    __syncthreads();
  }
  const float sc = 1.f / 512.f;
  float2* y2 = (float2*)(y + (size_t)bf * 1024);
#pragma unroll
  for (int u = 0; u < 2; ++u) {
    int n = tid + u * 256;
    y2[n] = make_float2(zr[n] * sc, zi[n] * sc);
  }
}

// ---------------- generic fp32 GEMM: C[M,N] = A[M,K] @ W[N,K]^T (+bias)(+epilogue)
// MODE 0: C = v            (bias optional)
// MODE 1: s = sigmoid(v); em = s*aux1; aux2 *= em; aux3 *= em   (mask1 -> est re/im)
// MODE 2: s = sigmoid(v); C = s*aux1                             (mask2 -> est2)
template <int MODE>
__global__ __launch_bounds__(256) void gemm_nt(
    const float* __restrict__ A, const float* __restrict__ W,
    const float* __restrict__ bias, float* __restrict__ C, int M, int N, int K,
    const float* __restrict__ aux1, float* __restrict__ aux2,
    float* __restrict__ aux3) {
  __shared__ float As[16][68];
  __shared__ float Ws[16][68];
  int tid = threadIdx.x;
  int tx = tid & 15, ty = tid >> 4;
  int m0 = blockIdx.y * 64, n0 = blockIdx.x * 64;
  float acc[4][4] = {};
  int klc = tid & 15;
  int rl = tid >> 4;
  for (int k0 = 0; k0 < K; k0 += 16) {
#pragma unroll
    for (int r = 0; r < 4; ++r) {
      int row = rl + r * 16;
      int m = m0 + row;
      int k = k0 + klc;
      As[klc][row] = (m < M && k < K) ? A[(size_t)m * K + k] : 0.f;
      int n = n0 + row;
      Ws[klc][row] = (n < N && k < K) ? W[(size_t)n * K + k] : 0.f;
    }
    __syncthreads();
#pragma unroll
    for (int kk = 0; kk < 16; ++kk) {
      float4 a4 = *reinterpret_cast<const float4*>(&As[kk][ty * 4]);
      float4 w4 = *reinterpret_cast<const float4*>(&Ws[kk][tx * 4]);
      float av[4] = {a4.x, a4.y, a4.z, a4.w};
      float wv[4] = {w4.x, w4.y, w4.z, w4.w};
#pragma unroll
      for (int i = 0; i < 4; ++i)
#pragma unroll
        for (int j = 0; j < 4; ++j)
          acc[i][j] = fmaf(av[i], wv[j], acc[i][j]);
    }
    __syncthreads();
  }
#pragma unroll
  for (int i = 0; i < 4; ++i) {
    int m = m0 + ty * 4 + i;
    if (m >= M) continue;
#pragma unroll
    for (int j = 0; j < 4; ++j) {
      int n = n0 + tx * 4 + j;
      if (n >= N) continue;
      float v = acc[i][j];
      if (bias) v += bias[n];
      size_t idx = (size_t)m * N + n;
      if (MODE == 0) {
        C[idx] = v;
      } else if (MODE == 1) {
        float s = sigmoidf_(v);
        float em = s * aux1[idx];
        aux2[idx] = em * aux2[idx];
        aux3[idx] = em * aux3[idx];
      } else {
        float s = sigmoidf_(v);
        C[idx] = s * aux1[idx];
      }
    }
  }
}

// ---------------- GRU recurrent scan (input gates xg precomputed)
// split-K x2: 768 threads; thread pair (2r,2r+1) owns gate row r, each half
// holds 64 weights (16 x float4 = 64 VGPRs) -> register-resident. Dot via
// packed-f4 FMA on b128 LDS broadcast reads; halves combined by shfl_xor(1).
__global__ __launch_bounds__(768, 3) void gru_scan(
    const float* __restrict__ xg,   // [B, F, 384]
    const float* __restrict__ Whh,  // [384, 128]
    const float* __restrict__ bhh,  // [384]
    const float* __restrict__ h0,   // [B, 128]
    float* __restrict__ hout,       // [B, F, 128]
    float* __restrict__ hlast,      // [B, 128]
    int F) {
  __shared__ __align__(16) float h_s[128];
  __shared__ float a_s[384];
  __shared__ float xn_s[128];
  int b = blockIdx.x;
  int tid = threadIdx.x;
  int row = tid >> 1;   // 0..383
  int half = tid & 1;   // 0/1
  const float* wrow = Whh + (size_t)row * 128 + half * 64;
  v4f w[16];
#pragma unroll
  for (int k = 0; k < 16; ++k)
    w[k] = *reinterpret_cast<const v4f*>(wrow + 4 * k);
#pragma unroll
  for (int k = 0; k < 16; ++k) asm volatile("" : "+v"(w[k]));
  float bh = (half == 0) ? bhh[row] : 0.f;
  if (tid < 128) h_s[tid] = h0[b * 128 + tid];
  const float* xgb = xg + (size_t)b * F * 384 + row;
  float* hob = hout + (size_t)b * F * 128;
  float xv_cur = (half == 0) ? xgb[0] : 0.f;
  __syncthreads();
  for (int t = 0; t < F; ++t) {
    // prefetch next step's input gate (half0 threads only)
    float xv_nxt = (half == 0 && t + 1 < F) ? xgb[(size_t)(t + 1) * 384] : 0.f;
    const v4f* h4 = reinterpret_cast<const v4f*>(h_s + half * 64);
    v4f a0 = {0.f, 0.f, 0.f, 0.f}, a1 = a0, a2 = a0, a3 = a0;
#pragma unroll
    for (int k = 0; k < 16; k += 4) {
      a0 = __builtin_elementwise_fma(w[k + 0], h4[k + 0], a0);
      a1 = __builtin_elementwise_fma(w[k + 1], h4[k + 1], a1);
      a2 = __builtin_elementwise_fma(w[k + 2], h4[k + 2], a2);
      a3 = __builtin_elementwise_fma(w[k + 3], h4[k + 3], a3);
    }
    v4f sv = (a0 + a1) + (a2 + a3);
    float s = (sv.x + sv.y) + (sv.z + sv.w);
    s += __shfl_xor(s, 1);  // combine halves (adjacent lanes)
    if (half == 0) {
      float acc = bh + s;
      if (row < 256) {
        a_s[row] = xv_cur + acc;
      } else {
        a_s[row] = acc;
        xn_s[row - 256] = xv_cur;
      }
    }
    __syncthreads();
    if (tid < 128) {
      float r = sigmoidf_(a_s[tid]);
      float z = sigmoidf_(a_s[128 + tid]);
      float nv = tanhf_(xn_s[tid] + r * a_s[256 + tid]);
      float hn = (1.f - z) * nv + z * h_s[tid];
      h_s[tid] = hn;
      hob[(size_t)t * 128 + tid] = hn;
    }
    xv_cur = xv_nxt;
    __syncthreads();
  }
  if (tid < 128) hlast[b * 128 + tid] = h_s[tid];
}

// ---------------- instant layernorm over channels (256)
__global__ __launch_bounds__(256) void ln_kernel(
    const float* __restrict__ enc, const float* __restrict__ gamma,
    const float* __restrict__ beta, float* __restrict__ out) {
  int row = blockIdx.x * 4 + (threadIdx.x >> 6);
  int lane = threadIdx.x & 63;
  const float* p = enc + (size_t)row * ENCn;
  float4 v = *reinterpret_cast<const float4*>(p + lane * 4);
  float s = v.x + v.y + v.z + v.w;
  float ss = v.x * v.x + v.y * v.y + v.z * v.z + v.w * v.w;
#pragma unroll
  for (int o = 32; o > 0; o >>= 1) {
    s += __shfl_down(s, o);
    ss += __shfl_down(ss, o);
  }
  s = __shfl(s, 0);
  ss = __shfl(ss, 0);
  float mean = s * (1.f / 256.f);
  float var = ss * (1.f / 256.f) - mean * mean;
  float rstd = rsqrtf(var + 1e-7f);
  float4 g4 = *reinterpret_cast<const float4*>(gamma + lane * 4);
  float4 b4 = *reinterpret_cast<const float4*>(beta + lane * 4);
  float4 o4;
  o4.x = (v.x - mean) * rstd * g4.x + b4.x;
  o4.y = (v.y - mean) * rstd * g4.y + b4.y;
  o4.z = (v.z - mean) * rstd * g4.z + b4.z;
  o4.w = (v.w - mean) * rstd * g4.w + b4.w;
  *reinterpret_cast<float4*>(out + (size_t)row * ENCn + lane * 4) = o4;
}

// ---------------- overlap-add
__global__ __launch_bounds__(256) void ola_kernel(const float* __restrict__ dec,
                                                  float* __restrict__ out) {
  int idx = blockIdx.x * 256 + threadIdx.x;  // b*T + n
  int b = idx >> 18;                          // T = 2^18
  int n = idx & (T_LEN - 1);
  int f0 = (n < 768) ? 0 : ((n - 768) >> 8);
  int f1 = min(n >> 8, F_FRAMES - 1);
  float s = 0.f;
  for (int f = f0; f <= f1; ++f)
    s += dec[((size_t)b * F_FRAMES + f) * 1024 + (n - (f << 8))];
  out[idx] = s;
}

extern "C" void kernel_launch(void* const* d_in, const int* in_sizes, int n_in,
                              void* d_out, int out_size, void* d_ws,
                              size_t ws_size, hipStream_t stream) {
  const float* x = (const float*)d_in[0];
  const float* in_st1 = (const float*)d_in[1];
  const float* in_st2 = (const float*)d_in[2];
  const float* s1_Wih1 = (const float*)d_in[3];
  const float* s1_Whh1 = (const float*)d_in[4];
  const float* s1_bih1 = (const float*)d_in[5];
  const float* s1_bhh1 = (const float*)d_in[6];
  const float* s1_Wih2 = (const float*)d_in[7];
  const float* s1_Whh2 = (const float*)d_in[8];
  const float* s1_bih2 = (const float*)d_in[9];
  const float* s1_bhh2 = (const float*)d_in[10];
  const float* s1_Wd = (const float*)d_in[11];
  const float* s1_bd = (const float*)d_in[12];
  const float* enc_W = (const float*)d_in[13];
  const float* gamma = (const float*)d_in[14];
  const float* beta = (const float*)d_in[15];
  const float* s2_Wih1 = (const float*)d_in[16];
  const float* s2_Whh1 = (const float*)d_in[17];
  const float* s2_bih1 = (const float*)d_in[18];
  const float* s2_bhh1 = (const float*)d_in[19];
  const float* s2_Wih2 = (const float*)d_in[20];
  const float* s2_Whh2 = (const float*)d_in[21];
  const float* s2_bih2 = (const float*)d_in[22];
  const float* s2_bhh2 = (const float*)d_in[23];
  const float* s2_Wd = (const float*)d_in[24];
  const float* s2_bd = (const float*)d_in[25];
  const float* dec_W = (const float*)d_in[26];

  float* out = (float*)d_out;
  float* st_out = out + (size_t)BATCH * T_LEN;  // [2,16,128] + [2,16,128]

  float* ws = (float*)d_ws;
  float* mag = ws;                              // BF*513
  float* cosp = mag + (size_t)BF * FREQn;       // BF*513 (-> est_re)
  float* sinp = cosp + (size_t)BF * FREQn;      // BF*513 (-> est_im)
  float* xgA = sinp + (size_t)BF * FREQn;       // BF*384
  float* xgB = xgA + (size_t)BF * 384;          // BF*384
  float* h1 = xgB + (size_t)BF * 384;           // BF*128
  float* h2 = h1 + (size_t)BF * HID;            // BF*128
  float* ybuf = h2 + (size_t)BF * HID;          // BF*1024 (y1, then dec)
  float* enc = ybuf + (size_t)BF * 1024;        // BF*256
  float* encn = enc + (size_t)BF * ENCn;        // BF*256 (enc_norm, then est2)

  auto gg = [](int M, int N) { return dim3((N + 63) / 64, (M + 63) / 64); };

  // 1. STFT -> mag, cos, sin
  stft_kernel<<<BF, 256, 0, stream>>>(x, mag, cosp, sinp);
  // 2. sep1 GRU-a input gates
  gemm_nt<0><<<gg(BF, 384), 256, 0, stream>>>(mag, s1_Wih1, s1_bih1, xgA, BF,
                                              384, FREQn, nullptr, nullptr,
                                              nullptr);
  // 3. scan a
  gru_scan<<<BATCH, 768, 0, stream>>>(xgA, s1_Whh1, s1_bhh1, in_st1, h1,
                                      st_out, F_FRAMES);
  // 4. sep1 GRU-b input gates
  gemm_nt<0><<<gg(BF, 384), 256, 0, stream>>>(h1, s1_Wih2, s1_bih2, xgB, BF,
                                              384, HID, nullptr, nullptr,
                                              nullptr);
  // 5. scan b
  gru_scan<<<BATCH, 768, 0, stream>>>(xgB, s1_Whh2, s1_bhh2, in_st1 + 2048, h2,
                                      st_out + 2048, F_FRAMES);
  // 6. mask1 dense + est spectrum (overwrites cosp/sinp)
  gemm_nt<1><<<gg(BF, FREQn), 256, 0, stream>>>(h2, s1_Wd, s1_bd, nullptr, BF,
                                                FREQn, HID, mag, cosp, sinp);
  // 7. iSTFT -> y1
  istft_kernel<<<BF, 256, 0, stream>>>(cosp, sinp, ybuf);
  // 8. encoder
  gemm_nt<0><<<gg(BF, ENCn), 256, 0, stream>>>(ybuf, enc_W, nullptr, enc, BF,
                                               ENCn, 1024, nullptr, nullptr,
                                               nullptr);
  // 9. instant LN
  ln_kernel<<<BF / 4, 256, 0, stream>>>(enc, gamma, beta, encn);
  // 10. sep2 GRU-a input gates
  gemm_nt<0><<<gg(BF, 384), 256, 0, stream>>>(encn, s2_Wih1, s2_bih1, xgA, BF,
                                              384, ENCn, nullptr, nullptr,
                                              nullptr);
  // 11. scan 2a
  gru_scan<<<BATCH, 768, 0, stream>>>(xgA, s2_Whh1, s2_bhh1, in_st2, h1,
                                      st_out + 4096, F_FRAMES);
  // 12. sep2 GRU-b input gates
  gemm_nt<0><<<gg(BF, 384), 256, 0, stream>>>(h1, s2_Wih2, s2_bih2, xgB, BF,
                                              384, HID, nullptr, nullptr,
                                              nullptr);
  // 13. scan 2b
  gru_scan<<<BATCH, 768, 0, stream>>>(xgB, s2_Whh2, s2_bhh2, in_st2 + 2048, h2,
                                      st_out + 6144, F_FRAMES);
  // 14. mask2 -> est2 (reads enc, writes encn)
  gemm_nt<2><<<gg(BF, ENCn), 256, 0, stream>>>(h2, s2_Wd, s2_bd, encn, BF,
                                               ENCn, HID, enc, nullptr,
                                               nullptr);
  // 15. decoder (reuses ybuf)
  gemm_nt<0><<<gg(BF, 1024), 256, 0, stream>>>(encn, dec_W, nullptr, ybuf, BF,
                                               1024, ENCn, nullptr, nullptr,
                                               nullptr);
  // 16. overlap-add
  ola_kernel<<<(BATCH * T_LEN) / 256, 256, 0, stream>>>(ybuf, out);
}

// Round 5
// 3922.027 us; speedup vs baseline: 1.5895x; 1.4070x over previous
//
#include <hip/hip_runtime.h>
#include <math.h>

#define F_FRAMES 1021
#define BATCH 16
#define T_LEN 262144
#define FREQn 513
#define HID 128
#define ENCn 256
#define BF (BATCH * F_FRAMES)  // 16336

typedef float v4f __attribute__((ext_vector_type(4)));

__device__ __forceinline__ float sigmoidf_(float x) {
  return 1.f / (1.f + __expf(-x));
}
__device__ __forceinline__ float tanhf_(float x) {
  // 1 - 2/(e^{2x}+1): monotone, no NaN for any finite x
  return 1.f - 2.f / (__expf(2.f * x) + 1.f);
}

// ---------------- STFT: frame + window + rfft(1024) -> mag, cos(phase), sin(phase)
__global__ __launch_bounds__(256) void stft_kernel(
    const float* __restrict__ x, float* __restrict__ mag,
    float* __restrict__ cosp, float* __restrict__ sinp) {
  __shared__ float zr[512], zi[512];
  int bf = blockIdx.x;
  int b = bf / F_FRAMES;
  int f = bf - b * F_FRAMES;
  const float* xb = x + (size_t)b * T_LEN + (size_t)f * 256;
  int tid = threadIdx.x;
  const float wstep = 6.28318530717958647692f / 1024.f;
#pragma unroll
  for (int u = 0; u < 2; ++u) {
    int j = tid + u * 256;
    int n = __brev((unsigned)j) >> 23;  // 9-bit bit-reverse
    float x0 = xb[2 * n] * (0.5f - 0.5f * __cosf((float)(2 * n) * wstep));
    float x1 = xb[2 * n + 1] * (0.5f - 0.5f * __cosf((float)(2 * n + 1) * wstep));
    zr[j] = x0;
    zi[j] = x1;
  }
  __syncthreads();
#pragma unroll
  for (int s = 1; s <= 9; ++s) {
    int half = 1 << (s - 1);
    int t = tid & (half - 1);
    int g = tid >> (s - 1);
    int pos = (g << s) + t;
    float ang = (float)t * (3.14159265358979323846f / (float)half);
    float sn, cs;
    __sincosf(ang, &sn, &cs);
    float wr = cs, wi = -sn;
    float ar = zr[pos], ai = zi[pos];
    float br = zr[pos + half], bi = zi[pos + half];
    float tr = wr * br - wi * bi;
    float ti = wr * bi + wi * br;
    zr[pos] = ar + tr;
    zi[pos] = ai + ti;
    zr[pos + half] = ar - tr;
    zi[pos + half] = ai - ti;
    __syncthreads();
  }
  const float eps = 1.1920928955078125e-07f;
  for (int k = tid; k < 513; k += 256) {
    int ka = k & 511;
    int kb = (512 - k) & 511;
    float zar = zr[ka], zai = zi[ka];
    float zbr = zr[kb], zbi = zi[kb];
    float Zer = 0.5f * (zar + zbr);
    float Zei = 0.5f * (zai - zbi);
    float Zor = 0.5f * (zai + zbi);
    float Zoi = -0.5f * (zar - zbr);
    float ang = (float)k * (3.14159265358979323846f / 512.f);
    float sn, cs;
    __sincosf(ang, &sn, &cs);
    float Wr = cs, Wi = -sn;
    float re = Zer + Wr * Zor - Wi * Zoi;
    float im = Zei + Wr * Zoi + Wi * Zor;
    size_t idx = (size_t)bf * FREQn + k;
    float p2 = re * re + im * im;
    mag[idx] = sqrtf(fmaxf(p2, eps));
    float rr = re + eps, ii = im + eps;
    float inv = rsqrtf(rr * rr + ii * ii);
    cosp[idx] = rr * inv;
    sinp[idx] = ii * inv;
  }
}

// ---------------- iSTFT: est spectrum -> irfft(1024) frames
__global__ __launch_bounds__(256) void istft_kernel(
    const float* __restrict__ er, const float* __restrict__ ei,
    float* __restrict__ y) {
  __shared__ float xr[513], xi[513];
  __shared__ float zr[512], zi[512];
  int bf = blockIdx.x;
  int tid = threadIdx.x;
  for (int k = tid; k < 513; k += 256) {
    size_t idx = (size_t)bf * FREQn + k;
    xr[k] = er[idx];
    float v = ei[idx];
    xi[k] = (k == 0 || k == 512) ? 0.f : v;  // pocketfft c2r ignores DC/Nyquist imag
  }
  __syncthreads();
#pragma unroll
  for (int u = 0; u < 2; ++u) {
    int k = tid + u * 256;  // 0..511
    int kk = 512 - k;
    float Xkr = xr[k], Xki = xi[k];
    float Xbr = xr[kk], Xbi = xi[kk];
    float Zer = 0.5f * (Xkr + Xbr);
    float Zei = 0.5f * (Xki - Xbi);
    float Vr = 0.5f * (Xkr - Xbr);
    float Vi = 0.5f * (Xki + Xbi);
    float ang = (float)k * (3.14159265358979323846f / 512.f);
    float sn, cs;
    __sincosf(ang, &sn, &cs);
    float Zor = cs * Vr - sn * Vi;  // e^{+i pi k/512} * V
    float Zoi = cs * Vi + sn * Vr;
    float Rr = Zer - Zoi;  // Z = Ze + i*Zo
    float Ri = Zei + Zor;
    int d = __brev((unsigned)k) >> 23;
    zr[d] = Rr;
    zi[d] = Ri;
  }
  __syncthreads();
#pragma unroll
  for (int s = 1; s <= 9; ++s) {
    int half = 1 << (s - 1);
    int t = tid & (half - 1);
    int g = tid >> (s - 1);
    int pos = (g << s) + t;
    float ang = (float)t * (3.14159265358979323846f / (float)half);
    float sn, cs;
    __sincosf(ang, &sn, &cs);
    float wr = cs, wi = sn;  // conjugate twiddles => unnormalized IDFT
    float ar = zr[pos], ai = zi[pos];
    float br = zr[pos + half], bi = zi[pos + half];
    float tr = wr * br - wi * bi;
    float ti = wr * bi + wi * br;
    zr[pos] = ar + tr;
    zi[pos] = ai + ti;
    zr[pos + half] = ar - tr;
    zi[pos + half] = ai - ti;
    __syncthreads();
  }
  const float sc = 1.f / 512.f;
  float2* y2 = (float2*)(y + (size_t)bf * 1024);
#pragma unroll
  for (int u = 0; u < 2; ++u) {
    int n = tid + u * 256;
    y2[n] = make_float2(zr[n] * sc, zi[n] * sc);
  }
}

// ---------------- generic fp32 GEMM: C[M,N] = A[M,K] @ W[N,K]^T (+bias)(+epilogue)
// MODE 0: C = v            (bias optional)
// MODE 1: s = sigmoid(v); em = s*aux1; aux2 *= em; aux3 *= em   (mask1 -> est re/im)
// MODE 2: s = sigmoid(v); C = s*aux1                             (mask2 -> est2)
template <int MODE>
__global__ __launch_bounds__(256) void gemm_nt(
    const float* __restrict__ A, const float* __restrict__ W,
    const float* __restrict__ bias, float* __restrict__ C, int M, int N, int K,
    const float* __restrict__ aux1, float* __restrict__ aux2,
    float* __restrict__ aux3) {
  __shared__ float As[16][68];
  __shared__ float Ws[16][68];
  int tid = threadIdx.x;
  int tx = tid & 15, ty = tid >> 4;
  int m0 = blockIdx.y * 64, n0 = blockIdx.x * 64;
  float acc[4][4] = {};
  int klc = tid & 15;
  int rl = tid >> 4;
  for (int k0 = 0; k0 < K; k0 += 16) {
#pragma unroll
    for (int r = 0; r < 4; ++r) {
      int row = rl + r * 16;
      int m = m0 + row;
      int k = k0 + klc;
      As[klc][row] = (m < M && k < K) ? A[(size_t)m * K + k] : 0.f;
      int n = n0 + row;
      Ws[klc][row] = (n < N && k < K) ? W[(size_t)n * K + k] : 0.f;
    }
    __syncthreads();
#pragma unroll
    for (int kk = 0; kk < 16; ++kk) {
      float4 a4 = *reinterpret_cast<const float4*>(&As[kk][ty * 4]);
      float4 w4 = *reinterpret_cast<const float4*>(&Ws[kk][tx * 4]);
      float av[4] = {a4.x, a4.y, a4.z, a4.w};
      float wv[4] = {w4.x, w4.y, w4.z, w4.w};
#pragma unroll
      for (int i = 0; i < 4; ++i)
#pragma unroll
        for (int j = 0; j < 4; ++j)
          acc[i][j] = fmaf(av[i], wv[j], acc[i][j]);
    }
    __syncthreads();
  }
#pragma unroll
  for (int i = 0; i < 4; ++i) {
    int m = m0 + ty * 4 + i;
    if (m >= M) continue;
#pragma unroll
    for (int j = 0; j < 4; ++j) {
      int n = n0 + tx * 4 + j;
      if (n >= N) continue;
      float v = acc[i][j];
      if (bias) v += bias[n];
      size_t idx = (size_t)m * N + n;
      if (MODE == 0) {
        C[idx] = v;
      } else if (MODE == 1) {
        float s = sigmoidf_(v);
        float em = s * aux1[idx];
        aux2[idx] = em * aux2[idx];
        aux3[idx] = em * aux3[idx];
      } else {
        float s = sigmoidf_(v);
        C[idx] = s * aux1[idx];
      }
    }
  }
}

// ---------------- GRU recurrent scan (input gates xg precomputed)
// split-K x2: 768 threads; thread pair (2r,2r+1) owns gate row r, each half
// holds 64 weights in 16 NAMED v4f locals (no array -> nothing addressable ->
// SROA keeps them in VGPRs; arrays+asm pins forced scratch in rounds 2-4).
// h halves skewed by 4 floats in LDS to decorrelate banks.
__global__ __launch_bounds__(768, 3) void gru_scan(
    const float* __restrict__ xg,   // [B, F, 384]
    const float* __restrict__ Whh,  // [384, 128]
    const float* __restrict__ bhh,  // [384]
    const float* __restrict__ h0,   // [B, 128]
    float* __restrict__ hout,       // [B, F, 128]
    float* __restrict__ hlast,      // [B, 128]
    int F) {
  __shared__ __align__(16) float h_s[136];  // half0 @0..63, half1 @68..131
  __shared__ float a_s[384];
  __shared__ float xn_s[128];
  int b = blockIdx.x;
  int tid = threadIdx.x;
  int row = tid >> 1;   // 0..383
  int half = tid & 1;   // 0/1
  const v4f* wrow = reinterpret_cast<const v4f*>(Whh + (size_t)row * 128 + half * 64);
  v4f w0 = wrow[0], w1 = wrow[1], w2 = wrow[2], w3 = wrow[3];
  v4f w4 = wrow[4], w5 = wrow[5], w6 = wrow[6], w7 = wrow[7];
  v4f w8 = wrow[8], w9 = wrow[9], w10 = wrow[10], w11 = wrow[11];
  v4f w12 = wrow[12], w13 = wrow[13], w14 = wrow[14], w15 = wrow[15];
  float bh = (half == 0) ? bhh[row] : 0.f;
  if (tid < 128) h_s[tid + (tid >> 6) * 4] = h0[b * 128 + tid];
  const float* xgb = xg + (size_t)b * F * 384 + row;
  float* hob = hout + (size_t)b * F * 128;
  float xv_cur = (half == 0) ? xgb[0] : 0.f;
  __syncthreads();
  for (int t = 0; t < F; ++t) {
    // prefetch next step's input gate (half0 threads only)
    float xv_nxt = (half == 0 && t + 1 < F) ? xgb[(size_t)(t + 1) * 384] : 0.f;
    const v4f* h4 = reinterpret_cast<const v4f*>(h_s + half * 68);
    v4f a0 = {0.f, 0.f, 0.f, 0.f}, a1 = a0, a2 = a0, a3 = a0;
    a0 = __builtin_elementwise_fma(w0, h4[0], a0);
    a1 = __builtin_elementwise_fma(w1, h4[1], a1);
    a2 = __builtin_elementwise_fma(w2, h4[2], a2);
    a3 = __builtin_elementwise_fma(w3, h4[3], a3);
    a0 = __builtin_elementwise_fma(w4, h4[4], a0);
    a1 = __builtin_elementwise_fma(w5, h4[5], a1);
    a2 = __builtin_elementwise_fma(w6, h4[6], a2);
    a3 = __builtin_elementwise_fma(w7, h4[7], a3);
    a0 = __builtin_elementwise_fma(w8, h4[8], a0);
    a1 = __builtin_elementwise_fma(w9, h4[9], a1);
    a2 = __builtin_elementwise_fma(w10, h4[10], a2);
    a3 = __builtin_elementwise_fma(w11, h4[11], a3);
    a0 = __builtin_elementwise_fma(w12, h4[12], a0);
    a1 = __builtin_elementwise_fma(w13, h4[13], a1);
    a2 = __builtin_elementwise_fma(w14, h4[14], a2);
    a3 = __builtin_elementwise_fma(w15, h4[15], a3);
    v4f sv = (a0 + a1) + (a2 + a3);
    float s = (sv.x + sv.y) + (sv.z + sv.w);
    s += __shfl_xor(s, 1);  // combine halves (adjacent lanes)
    if (half == 0) {
      float acc = bh + s;
      if (row < 256) {
        a_s[row] = xv_cur + acc;
      } else {
        a_s[row] = acc;
        xn_s[row - 256] = xv_cur;
      }
    }
    __syncthreads();
    if (tid < 128) {
      float r = sigmoidf_(a_s[tid]);
      float z = sigmoidf_(a_s[128 + tid]);
      float nv = tanhf_(xn_s[tid] + r * a_s[256 + tid]);
      float hn = (1.f - z) * nv + z * h_s[tid + (tid >> 6) * 4];
      h_s[tid + (tid >> 6) * 4] = hn;
      hob[(size_t)t * 128 + tid] = hn;
    }
    xv_cur = xv_nxt;
    __syncthreads();
  }
  if (tid < 128) hlast[b * 128 + tid] = h_s[tid + (tid >> 6) * 4];
}

// ---------------- instant layernorm over channels (256)
__global__ __launch_bounds__(256) void ln_kernel(
    const float* __restrict__ enc, const float* __restrict__ gamma,
    const float* __restrict__ beta, float* __restrict__ out) {
  int row = blockIdx.x * 4 + (threadIdx.x >> 6);
  int lane = threadIdx.x & 63;
  const float* p = enc + (size_t)row * ENCn;
  float4 v = *reinterpret_cast<const float4*>(p + lane * 4);
  float s = v.x + v.y + v.z + v.w;
  float ss = v.x * v.x + v.y * v.y + v.z * v.z + v.w * v.w;
#pragma unroll
  for (int o = 32; o > 0; o >>= 1) {
    s += __shfl_down(s, o);
    ss += __shfl_down(ss, o);
  }
  s = __shfl(s, 0);
  ss = __shfl(ss, 0);
  float mean = s * (1.f / 256.f);
  float var = ss * (1.f / 256.f) - mean * mean;
  float rstd = rsqrtf(var + 1e-7f);
  float4 g4 = *reinterpret_cast<const float4*>(gamma + lane * 4);
  float4 b4 = *reinterpret_cast<const float4*>(beta + lane * 4);
  float4 o4;
  o4.x = (v.x - mean) * rstd * g4.x + b4.x;
  o4.y = (v.y - mean) * rstd * g4.y + b4.y;
  o4.z = (v.z - mean) * rstd * g4.z + b4.z;
  o4.w = (v.w - mean) * rstd * g4.w + b4.w;
  *reinterpret_cast<float4*>(out + (size_t)row * ENCn + lane * 4) = o4;
}

// ---------------- overlap-add
__global__ __launch_bounds__(256) void ola_kernel(const float* __restrict__ dec,
                                                  float* __restrict__ out) {
  int idx = blockIdx.x * 256 + threadIdx.x;  // b*T + n
  int b = idx >> 18;                          // T = 2^18
  int n = idx & (T_LEN - 1);
  int f0 = (n < 768) ? 0 : ((n - 768) >> 8);
  int f1 = min(n >> 8, F_FRAMES - 1);
  float s = 0.f;
  for (int f = f0; f <= f1; ++f)
    s += dec[((size_t)b * F_FRAMES + f) * 1024 + (n - (f << 8))];
  out[idx] = s;
}

extern "C" void kernel_launch(void* const* d_in, const int* in_sizes, int n_in,
                              void* d_out, int out_size, void* d_ws,
                              size_t ws_size, hipStream_t stream) {
  const float* x = (const float*)d_in[0];
  const float* in_st1 = (const float*)d_in[1];
  const float* in_st2 = (const float*)d_in[2];
  const float* s1_Wih1 = (const float*)d_in[3];
  const float* s1_Whh1 = (const float*)d_in[4];
  const float* s1_bih1 = (const float*)d_in[5];
  const float* s1_bhh1 = (const float*)d_in[6];
  const float* s1_Wih2 = (const float*)d_in[7];
  const float* s1_Whh2 = (const float*)d_in[8];
  const float* s1_bih2 = (const float*)d_in[9];
  const float* s1_bhh2 = (const float*)d_in[10];
  const float* s1_Wd = (const float*)d_in[11];
  const float* s1_bd = (const float*)d_in[12];
  const float* enc_W = (const float*)d_in[13];
  const float* gamma = (const float*)d_in[14];
  const float* beta = (const float*)d_in[15];
  const float* s2_Wih1 = (const float*)d_in[16];
  const float* s2_Whh1 = (const float*)d_in[17];
  const float* s2_bih1 = (const float*)d_in[18];
  const float* s2_bhh1 = (const float*)d_in[19];
  const float* s2_Wih2 = (const float*)d_in[20];
  const float* s2_Whh2 = (const float*)d_in[21];
  const float* s2_bih2 = (const float*)d_in[22];
  const float* s2_bhh2 = (const float*)d_in[23];
  const float* s2_Wd = (const float*)d_in[24];
  const float* s2_bd = (const float*)d_in[25];
  const float* dec_W = (const float*)d_in[26];

  float* out = (float*)d_out;
  float* st_out = out + (size_t)BATCH * T_LEN;  // [2,16,128] + [2,16,128]

  float* ws = (float*)d_ws;
  float* mag = ws;                              // BF*513
  float* cosp = mag + (size_t)BF * FREQn;       // BF*513 (-> est_re)
  float* sinp = cosp + (size_t)BF * FREQn;      // BF*513 (-> est_im)
  float* xgA = sinp + (size_t)BF * FREQn;       // BF*384
  float* xgB = xgA + (size_t)BF * 384;          // BF*384
  float* h1 = xgB + (size_t)BF * 384;           // BF*128
  float* h2 = h1 + (size_t)BF * HID;            // BF*128
  float* ybuf = h2 + (size_t)BF * HID;          // BF*1024 (y1, then dec)
  float* enc = ybuf + (size_t)BF * 1024;        // BF*256
  float* encn = enc + (size_t)BF * ENCn;        // BF*256 (enc_norm, then est2)

  auto gg = [](int M, int N) { return dim3((N + 63) / 64, (M + 63) / 64); };

  // 1. STFT -> mag, cos, sin
  stft_kernel<<<BF, 256, 0, stream>>>(x, mag, cosp, sinp);
  // 2. sep1 GRU-a input gates
  gemm_nt<0><<<gg(BF, 384), 256, 0, stream>>>(mag, s1_Wih1, s1_bih1, xgA, BF,
                                              384, FREQn, nullptr, nullptr,
                                              nullptr);
  // 3. scan a
  gru_scan<<<BATCH, 768, 0, stream>>>(xgA, s1_Whh1, s1_bhh1, in_st1, h1,
                                      st_out, F_FRAMES);
  // 4. sep1 GRU-b input gates
  gemm_nt<0><<<gg(BF, 384), 256, 0, stream>>>(h1, s1_Wih2, s1_bih2, xgB, BF,
                                              384, HID, nullptr, nullptr,
                                              nullptr);
  // 5. scan b
  gru_scan<<<BATCH, 768, 0, stream>>>(xgB, s1_Whh2, s1_bhh2, in_st1 + 2048, h2,
                                      st_out + 2048, F_FRAMES);
  // 6. mask1 dense + est spectrum (overwrites cosp/sinp)
  gemm_nt<1><<<gg(BF, FREQn), 256, 0, stream>>>(h2, s1_Wd, s1_bd, nullptr, BF,
                                                FREQn, HID, mag, cosp, sinp);
  // 7. iSTFT -> y1
  istft_kernel<<<BF, 256, 0, stream>>>(cosp, sinp, ybuf);
  // 8. encoder
  gemm_nt<0><<<gg(BF, ENCn), 256, 0, stream>>>(ybuf, enc_W, nullptr, enc, BF,
                                               ENCn, 1024, nullptr, nullptr,
                                               nullptr);
  // 9. instant LN
  ln_kernel<<<BF / 4, 256, 0, stream>>>(enc, gamma, beta, encn);
  // 10. sep2 GRU-a input gates
  gemm_nt<0><<<gg(BF, 384), 256, 0, stream>>>(encn, s2_Wih1, s2_bih1, xgA, BF,
                                              384, ENCn, nullptr, nullptr,
                                              nullptr);
  // 11. scan 2a
  gru_scan<<<BATCH, 768, 0, stream>>>(xgA, s2_Whh1, s2_bhh1, in_st2, h1,
                                      st_out + 4096, F_FRAMES);
  // 12. sep2 GRU-b input gates
  gemm_nt<0><<<gg(BF, 384), 256, 0, stream>>>(h1, s2_Wih2, s2_bih2, xgB, BF,
                                              384, HID, nullptr, nullptr,
                                              nullptr);
  // 13. scan 2b
  gru_scan<<<BATCH, 768, 0, stream>>>(xgB, s2_Whh2, s2_bhh2, in_st2 + 2048, h2,
                                      st_out + 6144, F_FRAMES);
  // 14. mask2 -> est2 (reads enc, writes encn)
  gemm_nt<2><<<gg(BF, ENCn), 256, 0, stream>>>(h2, s2_Wd, s2_bd, encn, BF,
                                               ENCn, HID, enc, nullptr,
                                               nullptr);
  // 15. decoder (reuses ybuf)
  gemm_nt<0><<<gg(BF, 1024), 256, 0, stream>>>(encn, dec_W, nullptr, ybuf, BF,
                                               1024, ENCn, nullptr, nullptr,
                                               nullptr);
  // 16. overlap-add
  ola_kernel<<<(BATCH * T_LEN) / 256, 256, 0, stream>>>(ybuf, out);
}